// Round 21
// baseline (289.568 us; speedup 1.0000x reference)
//
#include <hip/hip_runtime.h>

// ---------------------------------------------------------------------------
// Swin-style windowed MHA block, MI355X/gfx950.
// R21: barrier-free decomposition, finally tested with the xpose fix (q<8).
// Evidence: mlp's 2048-small-block style does comparable GEMM work in ~55us
// while every mega-block attn sits latency-bound at 150-220us with all pipes
// <21%. Design (= R13 + xpose fix; bias stays f32 C-operand per R20 lesson):
//   prep      : weights->bf16 + biasx gather (f32, MFMA C-fragment layout).
//   xpose     : x (BCHW f32) -> xw[2048][64][192] bf16.  [q<8 FIX]
//   attn_core : 1 wave per (window,head), NO barriers, 4KB LDS. AO->global.
//   proj      : 1 wave per (window,64-col). y = x + proj in place over xw.
//   mlp       : R8-proven kernel, reads y (=xw), writes out fp32.
// ws = 101MB (R13 proved it allocates).
// ---------------------------------------------------------------------------

typedef short          s16x8 __attribute__((ext_vector_type(8)));
typedef unsigned short u16x4 __attribute__((ext_vector_type(4)));
typedef unsigned short u16x8 __attribute__((ext_vector_type(8)));
typedef float          f32x4 __attribute__((ext_vector_type(4)));

#define MFMA(A, B, C) __builtin_amdgcn_mfma_f32_16x16x32_bf16((A), (B), (C), 0, 0, 0)

__device__ __forceinline__ unsigned short f2b(float f) {
  unsigned x = __float_as_uint(f);
  x = (x + 0x7FFFu + ((x >> 16) & 1u)) >> 16;   // RNE
  return (unsigned short)x;
}
__device__ __forceinline__ float b2f(unsigned short u) {
  return __uint_as_float(((unsigned)u) << 16);
}
__device__ __forceinline__ u16x4 pk4(f32x4 v) {
  u16x4 r;
  r[0] = f2b(v[0]); r[1] = f2b(v[1]); r[2] = f2b(v[2]); r[3] = f2b(v[3]);
  return r;
}

// [64][32] tiles (Q,K,P-half): 16B-chunk XOR keyed on (t>>1)&3
__device__ __forceinline__ int swz32(int t, int c) {
  return t * 32 + ((((c >> 3) ^ (t >> 1)) & 3) << 3) + (c & 7);
}
// Vt [32][64]: chunk XOR keyed on (d + (d>>3)) & 7
__device__ __forceinline__ int swzV(int d, int t) {
  return d * 64 + ((((t >> 3) ^ (d + (d >> 3))) & 7) << 3) + (t & 7);
}

#define XSTR   200
#define QSCALE 0.17677669529663687f

// workspace offsets
#define WOFF_QKV   0            // u16 elems
#define WOFF_PROJ  110592
#define WOFF_MLP1  147456
#define WOFF_MLP2  221184
#define WOFF_BIASX_BYTES 516096               // float[4096] -> ends 532480
#define WOFF_XW_BYTES    532480               // u16[2048*64*192] (xw, then y in place)
#define WOFF_AOW_BYTES   50864128             // u16[2048*6*64*32]

// ---------------------------------------------------------------------------
__global__ void prep_kernel(const float* __restrict__ qkv_w,
                            const float* __restrict__ proj_w,
                            const float* __restrict__ mlp1_w,
                            const float* __restrict__ mlp2_w,
                            const float* __restrict__ bias_table,
                            const int*   __restrict__ rel_index,
                            unsigned short* __restrict__ qkv_wb,
                            unsigned short* __restrict__ proj_wb,
                            unsigned short* __restrict__ mlp1_wb,
                            unsigned short* __restrict__ mlp2_wb,
                            float* __restrict__ biasx) {
  int j = blockIdx.x * 256 + threadIdx.x;   // 262144 jobs
  if (j < 110592) {
    float v = qkv_w[j];
    if (j < 36864) v *= QSCALE;
    qkv_wb[j] = f2b(v);
  } else if (j < 147456) {
    proj_wb[j - 110592] = f2b(proj_w[j - 110592]);
  } else if (j < 221184) {
    mlp1_wb[j - 147456] = f2b(mlp1_w[j - 147456]);
  } else if (j < 258048) {
    mlp2_wb[j - 221184] = f2b(mlp2_w[j - 221184]);
  } else {
    int e = j - 258048;                     // 0..4095
    int l = e >> 6, v = e & 63;
    int tm = v >> 4, tn = (v >> 2) & 3, r = v & 3;
    int q = tn * 16 + (l & 15);
    int k = tm * 16 + (l >> 4) * 4 + r;
    biasx[e] = bias_table[rel_index[q * 64 + k]];
  }
}

// ---------------------------------------------------------------------------
// x [B=8][C=192][H=128][W=128] f32  ->  xw [2048][64][192] bf16
#define TSTR 129
__global__ __launch_bounds__(256) void xpose_kernel(
    const float* __restrict__ x, unsigned short* __restrict__ xw) {
  __shared__ unsigned short tb[192 * TSTR];  // 49536 B
  const int tid = threadIdx.x;
  const int s   = ((blockIdx.x & 7) << 7) | (blockIdx.x >> 3);  // XCD swizzle
  const int b   = s >> 7;
  const int hr  = s & 127;
  const float* xrow = x + (size_t)b * 192 * 16384 + (size_t)hr * 128;

  // stage: 192 c x 4 wseg (32 floats each) = 768 jobs; q<8 covers all 32
#pragma unroll
  for (int it = 0; it < 3; ++it) {
    int job = tid + 256 * it;
    int c = job >> 2, wseg = job & 3;
    const float* src = xrow + (size_t)c * 16384 + wseg * 32;
    unsigned short* dst = &tb[c * TSTR + wseg * 32];
#pragma unroll
    for (int q = 0; q < 8; ++q) {
      f32x4 v = *(const f32x4*)(src + q * 4);
      u16x4 p; p[0] = f2b(v[0]); p[1] = f2b(v[1]); p[2] = f2b(v[2]); p[3] = f2b(v[3]);
      *(u16x4*)&dst[q * 4] = p;
    }
  }
  __syncthreads();

  // write: 16 wwi x 8 w' x 24 cseg = 3072 jobs, 16B contiguous runs
  const int winb = b * 256 + (hr >> 3) * 16;
  const int i = hr & 7;
#pragma unroll
  for (int it = 0; it < 12; ++it) {
    int job = tid + 256 * it;
    int wwi = job / 192;
    int rem = job - wwi * 192;
    int t7 = rem / 24;
    int cseg = rem - t7 * 24;
    u16x8 v;
#pragma unroll
    for (int jj = 0; jj < 8; ++jj)
      v[jj] = tb[(cseg * 8 + jj) * TSTR + wwi * 8 + t7];
    unsigned short* dst = xw + (size_t)(winb + wwi) * 12288 + (i * 8 + t7) * 192 + cseg * 8;
    *(u16x8*)dst = v;
  }
}

// ---------------------------------------------------------------------------
// 1 wave per (window, head). No __syncthreads anywhere.
__global__ __launch_bounds__(64) void attn_core_kernel(
    const unsigned short* __restrict__ xw,
    const unsigned short* __restrict__ qkv_wb, const float* __restrict__ qkv_b,
    const float* __restrict__ biasx,
    unsigned short* __restrict__ aow) {
  __shared__ __align__(16) unsigned short sm[4096];   // R0 + R1 (2KB each)
  unsigned short* R0 = sm;
  unsigned short* R1 = sm + 2048;

  const int lane = threadIdx.x;
  const int l15  = lane & 15;
  const int lg   = lane >> 4;
  const int u    = (blockIdx.x & 7) * 1536 + (blockIdx.x >> 3);  // 12288 = 8*1536
  const int win  = u / 6;
  const int hd   = u - win * 6;
  const int oQ   = hd * 32;
  const unsigned short* xww = xw + (size_t)win * 12288;

  // ---------------- QKV: Q^T,K^T = mfma(w, x);  V = mfma(x, w) ----------------
  f32x4 accqT[2][4], acckT[2][4], accv[4][2];
#pragma unroll
  for (int m = 0; m < 2; ++m) {
    f32x4 bq4 = *(const f32x4*)&qkv_b[oQ + m * 16 + lg * 4];
    f32x4 bk4 = *(const f32x4*)&qkv_b[192 + oQ + m * 16 + lg * 4];
#pragma unroll
    for (int tn = 0; tn < 4; ++tn) {
      accqT[m][tn] = bq4 * QSCALE;
      acckT[m][tn] = bk4;
    }
  }
#pragma unroll
  for (int nt = 0; nt < 2; ++nt) {
    const float bv = qkv_b[384 + oQ + nt * 16 + l15];
#pragma unroll
    for (int mt = 0; mt < 4; ++mt) accv[mt][nt] = (f32x4){bv, bv, bv, bv};
  }
#pragma unroll
  for (int ks = 0; ks < 6; ++ks) {
    const int k0 = ks * 32 + lg * 8;
    s16x8 bf[4];
#pragma unroll
    for (int tn = 0; tn < 4; ++tn)
      bf[tn] = *(const s16x8*)&xww[(tn * 16 + l15) * 192 + k0];
    s16x8 wq[2], wk[2], wvv[2];
#pragma unroll
    for (int m = 0; m < 2; ++m) {
      wq[m]  = *(const s16x8*)&qkv_wb[(size_t)(oQ + m * 16 + l15) * 192 + k0];
      wk[m]  = *(const s16x8*)&qkv_wb[(size_t)(192 + oQ + m * 16 + l15) * 192 + k0];
      wvv[m] = *(const s16x8*)&qkv_wb[(size_t)(384 + oQ + m * 16 + l15) * 192 + k0];
    }
#pragma unroll
    for (int m = 0; m < 2; ++m)
#pragma unroll
      for (int tn = 0; tn < 4; ++tn) {
        accqT[m][tn] = MFMA(wq[m], bf[tn], accqT[m][tn]);
        acckT[m][tn] = MFMA(wk[m], bf[tn], acckT[m][tn]);
      }
#pragma unroll
    for (int mt = 0; mt < 4; ++mt)
#pragma unroll
      for (int nt = 0; nt < 2; ++nt)
        accv[mt][nt] = MFMA(bf[mt], wvv[nt], accv[mt][nt]);
  }
  // Q,K stores: C[d][t] regs run along d -> u16x4 into row-major [t][d]
#pragma unroll
  for (int m = 0; m < 2; ++m)
#pragma unroll
    for (int tn = 0; tn < 4; ++tn) {
      const int t = tn * 16 + l15, d0 = m * 16 + lg * 4;
      *(u16x4*)&R0[swz32(t, d0)] = pk4(accqT[m][tn]);
      *(u16x4*)&R1[swz32(t, d0)] = pk4(acckT[m][tn]);
    }
  u16x4 vreg[4][2];
#pragma unroll
  for (int mt = 0; mt < 4; ++mt)
#pragma unroll
    for (int nt = 0; nt < 2; ++nt)
      vreg[mt][nt] = pk4(accv[mt][nt]);

  // ---------------- scores^T = mfma(K, Q) + bias ----------------
  const float* bxp = biasx + lane * 64;
  s16x8 kf[4], qf[4];
#pragma unroll
  for (int tm = 0; tm < 4; ++tm)
    kf[tm] = *(const s16x8*)&R1[swz32(tm * 16 + l15, lg * 8)];
#pragma unroll
  for (int tn = 0; tn < 4; ++tn)
    qf[tn] = *(const s16x8*)&R0[swz32(tn * 16 + l15, lg * 8)];
  // Vt over K (in-wave DS order: after kf reads)
#pragma unroll
  for (int mt = 0; mt < 4; ++mt)
#pragma unroll
    for (int nt = 0; nt < 2; ++nt)
      *(u16x4*)&R1[swzV(nt * 16 + l15, mt * 16 + lg * 4)] = vreg[mt][nt];

  f32x4 sc[4][4];
#pragma unroll
  for (int tm = 0; tm < 4; ++tm)
#pragma unroll
    for (int tn = 0; tn < 4; ++tn) {
      f32x4 bfr = *(const f32x4*)&bxp[tm * 16 + tn * 4];
      sc[tm][tn] = MFMA(kf[tm], qf[tn], bfr);
    }
  // softmax over keys
#pragma unroll
  for (int tn = 0; tn < 4; ++tn) {
    float mx = sc[0][tn][0];
#pragma unroll
    for (int tm = 0; tm < 4; ++tm)
#pragma unroll
      for (int r = 0; r < 4; ++r) mx = fmaxf(mx, sc[tm][tn][r]);
    mx = fmaxf(mx, __shfl_xor(mx, 16));
    mx = fmaxf(mx, __shfl_xor(mx, 32));
    float sum = 0.f;
#pragma unroll
    for (int tm = 0; tm < 4; ++tm)
#pragma unroll
      for (int r = 0; r < 4; ++r) {
        float e = __expf(sc[tm][tn][r] - mx);
        sc[tm][tn][r] = e;
        sum += e;
      }
    sum += __shfl_xor(sum, 16);
    sum += __shfl_xor(sum, 32);
    const float inv = 1.0f / sum;
#pragma unroll
    for (int tm = 0; tm < 4; ++tm)
#pragma unroll
      for (int r = 0; r < 4; ++r) sc[tm][tn][r] *= inv;
  }

  // ---------------- PV as out^T = mfma(Vt, P), P in halves over R0 ----------------
  f32x4 oT[2][4];
#pragma unroll
  for (int m = 0; m < 2; ++m)
#pragma unroll
    for (int tn = 0; tn < 4; ++tn) oT[m][tn] = (f32x4){0.f, 0.f, 0.f, 0.f};
#pragma unroll
  for (int half = 0; half < 2; ++half) {
#pragma unroll
    for (int tm = 0; tm < 2; ++tm)
#pragma unroll
      for (int tn = 0; tn < 4; ++tn)
        *(u16x4*)&R0[swz32(tn * 16 + l15, tm * 16 + lg * 4)] =
            pk4(sc[half * 2 + tm][tn]);
    s16x8 bp[4], av[2];
#pragma unroll
    for (int tn = 0; tn < 4; ++tn)
      bp[tn] = *(const s16x8*)&R0[swz32(tn * 16 + l15, lg * 8)];
#pragma unroll
    for (int m = 0; m < 2; ++m)
      av[m] = *(const s16x8*)&R1[swzV(m * 16 + l15, half * 32 + lg * 8)];
#pragma unroll
    for (int m = 0; m < 2; ++m)
#pragma unroll
      for (int tn = 0; tn < 4; ++tn)
        oT[m][tn] = MFMA(av[m], bp[tn], oT[m][tn]);
  }
  // AO -> global aow[(win*6+hd)][t][d] (wave covers every 64B line fully)
  unsigned short* aoo = aow + (size_t)(win * 6 + hd) * 2048;
#pragma unroll
  for (int m = 0; m < 2; ++m)
#pragma unroll
    for (int tn = 0; tn < 4; ++tn) {
      const int t = tn * 16 + l15, d0 = m * 16 + lg * 4;
      *(u16x4*)&aoo[t * 32 + d0] = pk4(oT[m][tn]);
    }
}

// ---------------------------------------------------------------------------
// 1 wave per (window, 64-col group): proj + residual, y over xw in place.
__global__ __launch_bounds__(64) void proj_kernel(
    const unsigned short* __restrict__ aow,
    const unsigned short* __restrict__ proj_wb, const float* __restrict__ proj_b,
    unsigned short* __restrict__ xw /* becomes y in place */) {
  const int lane = threadIdx.x;
  const int l15  = lane & 15;
  const int lg   = lane >> 4;
  const int u    = (blockIdx.x & 7) * 768 + (blockIdx.x >> 3);   // 6144 = 8*768
  const int win  = u / 3;
  const int og   = u - win * 3;
  const int ob   = og * 64;

  f32x4 pjT[4][4];
#pragma unroll
  for (int mo = 0; mo < 4; ++mo) {
    f32x4 bp4 = *(const f32x4*)&proj_b[ob + mo * 16 + lg * 4];
#pragma unroll
    for (int tn = 0; tn < 4; ++tn) pjT[mo][tn] = bp4;
  }
#pragma unroll
  for (int hh = 0; hh < 6; ++hh) {
    const unsigned short* aoh = aow + (size_t)(win * 6 + hh) * 2048;
    s16x8 aa[4];
#pragma unroll
    for (int tn = 0; tn < 4; ++tn)
      aa[tn] = *(const s16x8*)&aoh[(tn * 16 + l15) * 32 + lg * 8];
    s16x8 wp[4];
#pragma unroll
    for (int mo = 0; mo < 4; ++mo)
      wp[mo] = *(const s16x8*)&proj_wb[(size_t)(ob + mo * 16 + l15) * 192 + hh * 32 + lg * 8];
#pragma unroll
    for (int mo = 0; mo < 4; ++mo)
#pragma unroll
      for (int tn = 0; tn < 4; ++tn)
        pjT[mo][tn] = MFMA(wp[mo], aa[tn], pjT[mo][tn]);
  }
  // y = x + proj, in place over xw (lane-private cells; full-line coverage)
  unsigned short* xwy = xw + (size_t)win * 12288;
#pragma unroll
  for (int mo = 0; mo < 4; ++mo)
#pragma unroll
    for (int tn = 0; tn < 4; ++tn) {
      const int t = tn * 16 + l15, o0 = ob + mo * 16 + lg * 4;
      u16x4 old = *(const u16x4*)&xwy[t * 192 + o0];
      f32x4 s;
#pragma unroll
      for (int r = 0; r < 4; ++r) s[r] = pjT[mo][tn][r] + b2f(old[r]);
      *(u16x4*)&xwy[t * 192 + o0] = pk4(s);
    }
}

// ---------------------------------------------------------------------------
__global__ __launch_bounds__(256, 4) void mlp_kernel(
    const unsigned short* __restrict__ y_win,
    const unsigned short* __restrict__ w1b, const float* __restrict__ b1,
    const unsigned short* __restrict__ w2b, const float* __restrict__ b2,
    float* __restrict__ out) {
  __shared__ __align__(16) unsigned short sm2[2 * 64 * XSTR];
  unsigned short* yb = sm2;
  unsigned short* wk = sm2 + 64 * XSTR;

  const int tid  = threadIdx.x;
  const int lane = tid & 63;
  const int wv   = tid >> 6;
  const int l15  = lane & 15;
  const int lg   = lane >> 4;
  const int win  = ((blockIdx.x & 7) << 8) | (blockIdx.x >> 3);
  const int bb   = win >> 8;
  const int wh   = (win >> 4) & 15;
  const int wwi  = win & 15;

  const unsigned short* ywp = y_win + (size_t)win * 12288;
#pragma unroll
  for (int it = 0; it < 6; ++it) {
    int job = tid + 256 * it;
    int t = job / 24;
    int seg = job - t * 24;
    *(u16x8*)&yb[t * XSTR + seg * 8] = *(const u16x8*)&ywp[(size_t)job * 8];
  }
  __syncthreads();

#pragma unroll
  for (int i = 0; i < 3; ++i) {
    const int na = (3 * wv + i) * 16 + l15;
    const int nb = na + 192;
    f32x4 aacc[4], bacc[4];
    const float ba = b1[na], bbv = b1[nb];
#pragma unroll
    for (int m = 0; m < 4; ++m) {
      aacc[m] = (f32x4){ba, ba, ba, ba};
      bacc[m] = (f32x4){bbv, bbv, bbv, bbv};
    }
#pragma unroll
    for (int ks = 0; ks < 6; ++ks) {
      const int k0 = ks * 32 + lg * 8;
      s16x8 af[4];
#pragma unroll
      for (int m = 0; m < 4; ++m)
        af[m] = *(const s16x8*)&yb[(m * 16 + l15) * XSTR + k0];
      s16x8 wa = *(const s16x8*)&w1b[(size_t)na * 192 + k0];
      s16x8 wb = *(const s16x8*)&w1b[(size_t)nb * 192 + k0];
#pragma unroll
      for (int m = 0; m < 4; ++m) {
        aacc[m] = MFMA(af[m], wa, aacc[m]);
        bacc[m] = MFMA(af[m], wb, bacc[m]);
      }
    }
#pragma unroll
    for (int m = 0; m < 4; ++m)
#pragma unroll
      for (int r = 0; r < 4; ++r) {
        const float g = aacc[m][r] * (1.0f / (1.0f + __expf(-bacc[m][r])));
        wk[(m * 16 + lg * 4 + r) * XSTR + na] = f2b(g);
      }
  }
  __syncthreads();

  int ocol[3];
  f32x4 macc[4][3];
#pragma unroll
  for (int i = 0; i < 3; ++i) {
    ocol[i] = (3 * wv + i) * 16 + l15;
    const float bb2 = b2[ocol[i]];
#pragma unroll
    for (int m = 0; m < 4; ++m) macc[m][i] = (f32x4){bb2, bb2, bb2, bb2};
  }
#pragma unroll
  for (int ks = 0; ks < 6; ++ks) {
    const int k0 = ks * 32 + lg * 8;
    s16x8 gf[4];
#pragma unroll
    for (int m = 0; m < 4; ++m)
      gf[m] = *(const s16x8*)&wk[(m * 16 + l15) * XSTR + k0];
#pragma unroll
    for (int i = 0; i < 3; ++i) {
      s16x8 wf = *(const s16x8*)&w2b[(size_t)ocol[i] * 192 + k0];
#pragma unroll
      for (int m = 0; m < 4; ++m) macc[m][i] = MFMA(gf[m], wf, macc[m][i]);
    }
  }
  __syncthreads();
#pragma unroll
  for (int m = 0; m < 4; ++m)
#pragma unroll
    for (int i = 0; i < 3; ++i)
#pragma unroll
      for (int r = 0; r < 4; ++r)
        wk[(m * 16 + lg * 4 + r) * XSTR + ocol[i]] = f2b(macc[m][i][r]);
  __syncthreads();

  float* obase = out + (size_t)bb * 192 * 16384 + (size_t)(wh * 8) * 128 + wwi * 8;
#pragma unroll
  for (int it = 0; it < 6; ++it) {
    int job = tid + 256 * it;
    int i = job / 192;
    int c = job - i * 192;
    float vals[8];
#pragma unroll
    for (int j = 0; j < 8; ++j) {
      const int t = i * 8 + j;
      vals[j] = b2f(yb[t * XSTR + c]) + b2f(wk[t * XSTR + c]);
    }
    float* dst = obase + (size_t)c * 16384 + i * 128;
    f32x4 o0 = {vals[0], vals[1], vals[2], vals[3]};
    f32x4 o1 = {vals[4], vals[5], vals[6], vals[7]};
    *(f32x4*)dst = o0;
    *(f32x4*)(dst + 4) = o1;
  }
}

// ---------------------------------------------------------------------------
extern "C" void kernel_launch(void* const* d_in, const int* in_sizes, int n_in,
                              void* d_out, int out_size, void* d_ws, size_t ws_size,
                              hipStream_t stream) {
  (void)in_sizes; (void)n_in; (void)out_size; (void)ws_size;
  const float* x          = (const float*)d_in[0];
  const float* qkv_w      = (const float*)d_in[1];
  const float* qkv_b      = (const float*)d_in[2];
  const float* proj_w     = (const float*)d_in[3];
  const float* proj_b     = (const float*)d_in[4];
  const float* mlp1_w     = (const float*)d_in[5];
  const float* mlp1_b     = (const float*)d_in[6];
  const float* mlp2_w     = (const float*)d_in[7];
  const float* mlp2_b     = (const float*)d_in[8];
  const float* bias_table = (const float*)d_in[9];
  const int*   rel_index  = (const int*)d_in[10];
  float* out = (float*)d_out;

  char* ws = (char*)d_ws;
  unsigned short* qkv_wb  = (unsigned short*)ws + WOFF_QKV;
  unsigned short* proj_wb = (unsigned short*)ws + WOFF_PROJ;
  unsigned short* mlp1_wb = (unsigned short*)ws + WOFF_MLP1;
  unsigned short* mlp2_wb = (unsigned short*)ws + WOFF_MLP2;
  float*          biasx   = (float*)(ws + WOFF_BIASX_BYTES);
  unsigned short* xw      = (unsigned short*)(ws + WOFF_XW_BYTES);   // xw, then y
  unsigned short* aow     = (unsigned short*)(ws + WOFF_AOW_BYTES);

  hipLaunchKernelGGL(prep_kernel, dim3(1024), dim3(256), 0, stream,
                     qkv_w, proj_w, mlp1_w, mlp2_w, bias_table, rel_index,
                     qkv_wb, proj_wb, mlp1_wb, mlp2_wb, biasx);
  hipLaunchKernelGGL(xpose_kernel, dim3(1024), dim3(256), 0, stream, x, xw);
  hipLaunchKernelGGL(attn_core_kernel, dim3(12288), dim3(64), 0, stream,
                     xw, qkv_wb, qkv_b, biasx, aow);
  hipLaunchKernelGGL(proj_kernel, dim3(6144), dim3(64), 0, stream,
                     aow, proj_wb, proj_b, xw);
  hipLaunchKernelGGL(mlp_kernel, dim3(2048), dim3(256), 0, stream,
                     xw, mlp1_wb, mlp1_b, mlp2_wb, mlp2_b, out);
}